// Round 9
// baseline (3950.209 us; speedup 1.0000x reference)
//
#include <hip/hip_runtime.h>
#include <math.h>

#define NN 100000
#define NE 1600000
#define DH 64
#define DO 40
#define NBKT ((NN + 255) >> 8)                 // 391 buckets of 256 rows
#define P3B 256                                 // blocks in binning passes
#define EPB ((NE + P3B - 1) / P3B)              // 6250 edges per block (exact)
#define RB 64                                   // rows per spmv tile
#define NRB ((NN + RB - 1) / RB)                // 1563 rowblocks
#define CWSH 13                                 // col window = 8192 rows (1 MB bf16)
#define NCW ((NN + (1 << CWSH) - 1) >> CWSH)    // 13 windows
#define NKEY (4 * NCW)                          // 52 keys per bucket (4 quarters x 13)

typedef __attribute__((ext_vector_type(8))) short bf16x8;
typedef __attribute__((ext_vector_type(4))) float f32x4;
typedef __attribute__((ext_vector_type(4))) unsigned short u16x4;

__device__ inline unsigned short f2bf(float f) {   // fp32 -> bf16 RNE
    unsigned u = __float_as_uint(f);
    u = (u + 0x7FFF + ((u >> 16) & 1)) >> 16;
    return (unsigned short)u;
}
__device__ inline float bf2f(unsigned short b) {
    return __uint_as_float((unsigned)b << 16);
}

// ---- pass 1: bucket histogram (LDS-aggregated) ----
__global__ __launch_bounds__(1024) void bin_count_kernel(const int* __restrict__ row,
                                                         int* __restrict__ bcnt) {
    __shared__ int h[NBKT];
    for (int i = threadIdx.x; i < NBKT; i += 1024) h[i] = 0;
    __syncthreads();
    int base = blockIdx.x * EPB;
    int end = base + EPB; if (end > NE) end = NE;
    for (int e = base + threadIdx.x; e < end; e += 1024)
        atomicAdd(&h[row[e] >> 8], 1);
    __syncthreads();
    for (int i = threadIdx.x; i < NBKT; i += 1024)
        if (h[i]) atomicAdd(&bcnt[i], h[i]);
}

// ---- pass 2: scan bucket counts -> bbase, gcur; rbptr[NRB] = NE ----
__global__ __launch_bounds__(512) void bscan_kernel(const int* __restrict__ bcnt,
                                                    int* __restrict__ bbase,
                                                    int* __restrict__ gcur,
                                                    int* __restrict__ rbptr) {
    __shared__ int tmp[512];
    int tid = threadIdx.x;
    int v = (tid < NBKT) ? bcnt[tid] : 0;
    tmp[tid] = v;
    __syncthreads();
    for (int off = 1; off < 512; off <<= 1) {
        int t = (tid >= off) ? tmp[tid - off] : 0;
        __syncthreads();
        tmp[tid] += t;
        __syncthreads();
    }
    if (tid < NBKT) { int excl = tmp[tid] - v; bbase[tid] = excl; gcur[tid] = excl; }
    if (tid == 0) { bbase[NBKT] = NE; rbptr[NRB] = NE; }
}

// ---- pass 3: scatter edges to bucket-contiguous order (LDS cursors) ----
// binned[pos] = ( (row_local8<<17) | col , w )
__global__ __launch_bounds__(1024) void bin_scatter_kernel(const int* __restrict__ row,
                                                           const int* __restrict__ col,
                                                           const float* __restrict__ w,
                                                           int* __restrict__ gcur,
                                                           int2* __restrict__ binned) {
    __shared__ int h[NBKT];
    __shared__ int cur[NBKT];
    for (int i = threadIdx.x; i < NBKT; i += 1024) h[i] = 0;
    __syncthreads();
    int base = blockIdx.x * EPB;
    int end = base + EPB; if (end > NE) end = NE;
    for (int e = base + threadIdx.x; e < end; e += 1024)
        atomicAdd(&h[row[e] >> 8], 1);
    __syncthreads();
    for (int i = threadIdx.x; i < NBKT; i += 1024)
        cur[i] = h[i] ? atomicAdd(&gcur[i], h[i]) : 0;
    __syncthreads();
    for (int e = base + threadIdx.x; e < end; e += 1024) {
        int r = row[e];
        int b = r >> 8;
        int pos = atomicAdd(&cur[b], 1);
        binned[pos] = make_int2(((r & 255) << 17) | col[e], __float_as_int(w[e]));
    }
}

// ---- pass 4: per-bucket finalize: deg/dinv; counting-sort edges by
//      (rowblock-quarter, col-window); emit (rl6, col, -w*dinv_row) ----
__global__ __launch_bounds__(1024) void bfin2_kernel(const int* __restrict__ bbase,
                                                     const int2* __restrict__ binned,
                                                     int* __restrict__ rbptr,
                                                     float* __restrict__ dinv,
                                                     int2* __restrict__ epack) {
    __shared__ float deg[256];
    __shared__ float sdv[256];
    __shared__ int sbc[NKEY];
    __shared__ int sbase[NKEY];
    __shared__ int scur[NKEY];
    int b = blockIdx.x;
    int s = bbase[b], t = bbase[b + 1];
    int tid = threadIdx.x;
    if (tid < 256) deg[tid] = 0.f;
    if (tid < NKEY) sbc[tid] = 0;
    __syncthreads();
    for (int i = s + tid; i < t; i += 1024) {
        int2 ep = binned[i];
        int rl = ((unsigned)ep.x) >> 17;
        int c = ep.x & 0x1FFFF;
        atomicAdd(&deg[rl], __int_as_float(ep.y));
        atomicAdd(&sbc[(rl >> 6) * NCW + (c >> CWSH)], 1);
    }
    __syncthreads();
    if (tid == 0) {
        int run = 0;
        for (int k = 0; k < NKEY; ++k) { sbase[k] = run; scur[k] = run; run += sbc[k]; }
    }
    if (tid < 256) {
        float d = deg[tid];
        float dv = d > 0.f ? 1.0f / sqrtf(d) : 0.f;
        sdv[tid] = dv;
        int r = (b << 8) + tid;
        if (r < NN) dinv[r] = dv;
    }
    __syncthreads();
    if (tid < 4) {
        int idx = b * 4 + tid;
        if (idx < NRB) rbptr[idx] = s + sbase[tid * NCW];
    }
    for (int i = s + tid; i < t; i += 1024) {
        int2 ep = binned[i];
        int rl = ((unsigned)ep.x) >> 17;
        int c = ep.x & 0x1FFFF;
        int key = (rl >> 6) * NCW + (c >> CWSH);
        int pos = s + atomicAdd(&scur[key], 1);
        float tp = -__int_as_float(ep.y) * sdv[rl];
        epack[pos] = make_int2(((rl & 63) << 17) | c, __float_as_int(tp));
    }
}

// ---- pass 5: env finalize: nv = t * dinv[col] ----
__global__ void env_kernel(const float* __restrict__ dinv, int2* __restrict__ epack) {
    int e = blockIdx.x * blockDim.x + threadIdx.x;
    if (e < NE) {
        int2 ep = epack[e];
        ep.y = __float_as_int(__int_as_float(ep.y) * dinv[ep.x & 0x1FFFF]);
        epack[e] = ep;
    }
}

// ---- x (f32) -> xb (bf16) ----
__global__ void x2bf_kernel(const float* __restrict__ x, unsigned short* __restrict__ xb) {
    int i = blockIdx.x * blockDim.x + threadIdx.x;
    if (i < NN * DH / 4) {
        float4 v = ((const float4*)x)[i];
        u16x4 o = {f2bf(v.x), f2bf(v.y), f2bf(v.z), f2bf(v.w)};
        ((u16x4*)xb)[i] = o;
    }
}

// ---- tiled SpMV: one block per 64-row tile, LDS f32 accumulators,
//      edges col-window-sorted -> synchronized sweep -> L2-resident gathers ----
__global__ __launch_bounds__(256) void spmv_tile_kernel(const int* __restrict__ rbptr,
                                                        const int2* __restrict__ epack,
                                                        const unsigned short* __restrict__ h,
                                                        unsigned short* __restrict__ y) {
    __shared__ float acc[RB * DH];   // 16 KB
    int rb = blockIdx.x;
    int tid = threadIdx.x;
    int lane = tid & 63, wq = tid >> 6;
    for (int i = tid; i < RB * DH; i += 256) acc[i] = 0.f;
    __syncthreads();
    int s = rbptr[rb], t = rbptr[rb + 1];
    // waves interleave 64-edge chunks so all 4 stay in the same col window
    for (int cb = s + wq * 64; cb < t; cb += 256) {
        int n = t - cb; if (n > 64) n = 64;
        int2 ep = make_int2(0, 0);
        if (lane < n) ep = epack[cb + lane];
        int i = 0;
        for (; i + 16 <= n; i += 16) {
            int   x0 = __shfl(ep.x, i);      float w0 = __int_as_float(__shfl(ep.y, i));
            int   x1 = __shfl(ep.x, i + 1);  float w1 = __int_as_float(__shfl(ep.y, i + 1));
            int   x2 = __shfl(ep.x, i + 2);  float w2 = __int_as_float(__shfl(ep.y, i + 2));
            int   x3 = __shfl(ep.x, i + 3);  float w3 = __int_as_float(__shfl(ep.y, i + 3));
            int   x4 = __shfl(ep.x, i + 4);  float w4 = __int_as_float(__shfl(ep.y, i + 4));
            int   x5 = __shfl(ep.x, i + 5);  float w5 = __int_as_float(__shfl(ep.y, i + 5));
            int   x6 = __shfl(ep.x, i + 6);  float w6 = __int_as_float(__shfl(ep.y, i + 6));
            int   x7 = __shfl(ep.x, i + 7);  float w7 = __int_as_float(__shfl(ep.y, i + 7));
            int   x8 = __shfl(ep.x, i + 8);  float w8 = __int_as_float(__shfl(ep.y, i + 8));
            int   x9 = __shfl(ep.x, i + 9);  float w9 = __int_as_float(__shfl(ep.y, i + 9));
            int   xA = __shfl(ep.x, i + 10); float wA = __int_as_float(__shfl(ep.y, i + 10));
            int   xB = __shfl(ep.x, i + 11); float wB = __int_as_float(__shfl(ep.y, i + 11));
            int   xC = __shfl(ep.x, i + 12); float wC = __int_as_float(__shfl(ep.y, i + 12));
            int   xD = __shfl(ep.x, i + 13); float wD = __int_as_float(__shfl(ep.y, i + 13));
            int   xE = __shfl(ep.x, i + 14); float wE = __int_as_float(__shfl(ep.y, i + 14));
            int   xF = __shfl(ep.x, i + 15); float wF = __int_as_float(__shfl(ep.y, i + 15));
            unsigned short h0 = h[(size_t)(x0 & 0x1FFFF) * DH + lane];
            unsigned short h1 = h[(size_t)(x1 & 0x1FFFF) * DH + lane];
            unsigned short h2 = h[(size_t)(x2 & 0x1FFFF) * DH + lane];
            unsigned short h3 = h[(size_t)(x3 & 0x1FFFF) * DH + lane];
            unsigned short h4 = h[(size_t)(x4 & 0x1FFFF) * DH + lane];
            unsigned short h5 = h[(size_t)(x5 & 0x1FFFF) * DH + lane];
            unsigned short h6 = h[(size_t)(x6 & 0x1FFFF) * DH + lane];
            unsigned short h7 = h[(size_t)(x7 & 0x1FFFF) * DH + lane];
            unsigned short h8 = h[(size_t)(x8 & 0x1FFFF) * DH + lane];
            unsigned short h9 = h[(size_t)(x9 & 0x1FFFF) * DH + lane];
            unsigned short hA = h[(size_t)(xA & 0x1FFFF) * DH + lane];
            unsigned short hB = h[(size_t)(xB & 0x1FFFF) * DH + lane];
            unsigned short hC = h[(size_t)(xC & 0x1FFFF) * DH + lane];
            unsigned short hD = h[(size_t)(xD & 0x1FFFF) * DH + lane];
            unsigned short hE = h[(size_t)(xE & 0x1FFFF) * DH + lane];
            unsigned short hF = h[(size_t)(xF & 0x1FFFF) * DH + lane];
            atomicAdd(&acc[(((unsigned)x0) >> 17) * DH + lane], w0 * bf2f(h0));
            atomicAdd(&acc[(((unsigned)x1) >> 17) * DH + lane], w1 * bf2f(h1));
            atomicAdd(&acc[(((unsigned)x2) >> 17) * DH + lane], w2 * bf2f(h2));
            atomicAdd(&acc[(((unsigned)x3) >> 17) * DH + lane], w3 * bf2f(h3));
            atomicAdd(&acc[(((unsigned)x4) >> 17) * DH + lane], w4 * bf2f(h4));
            atomicAdd(&acc[(((unsigned)x5) >> 17) * DH + lane], w5 * bf2f(h5));
            atomicAdd(&acc[(((unsigned)x6) >> 17) * DH + lane], w6 * bf2f(h6));
            atomicAdd(&acc[(((unsigned)x7) >> 17) * DH + lane], w7 * bf2f(h7));
            atomicAdd(&acc[(((unsigned)x8) >> 17) * DH + lane], w8 * bf2f(h8));
            atomicAdd(&acc[(((unsigned)x9) >> 17) * DH + lane], w9 * bf2f(h9));
            atomicAdd(&acc[(((unsigned)xA) >> 17) * DH + lane], wA * bf2f(hA));
            atomicAdd(&acc[(((unsigned)xB) >> 17) * DH + lane], wB * bf2f(hB));
            atomicAdd(&acc[(((unsigned)xC) >> 17) * DH + lane], wC * bf2f(hC));
            atomicAdd(&acc[(((unsigned)xD) >> 17) * DH + lane], wD * bf2f(hD));
            atomicAdd(&acc[(((unsigned)xE) >> 17) * DH + lane], wE * bf2f(hE));
            atomicAdd(&acc[(((unsigned)xF) >> 17) * DH + lane], wF * bf2f(hF));
        }
        for (; i < n; ++i) {
            int xv = __shfl(ep.x, i); float wv = __int_as_float(__shfl(ep.y, i));
            unsigned short hv = h[(size_t)(xv & 0x1FFFF) * DH + lane];
            atomicAdd(&acc[(((unsigned)xv) >> 17) * DH + lane], wv * bf2f(hv));
        }
    }
    __syncthreads();
    int rbase = rb * RB;
    for (int i = tid; i < RB * DH; i += 256) {
        int r = rbase + (i >> 6);
        if (r < NN) y[(size_t)r * DH + (i & 63)] = f2bf(acc[i]);
    }
}

// ---- weight prep: Wt[n][192] bf16, k = j*64+kin ----
// j=0: W[0]-W[2]; j=1: W[1]; j=2: 2*W[2]   (folds Tx2 = 2*y2 - Tx0 into weights)
__global__ void wprep_kernel(const float* __restrict__ W, int SW,
                             unsigned short* __restrict__ Wt) {
    int idx = blockIdx.x * 256 + threadIdx.x;
    if (idx >= 64 * 192) return;
    int n = idx / 192, k = idx - n * 192;
    int j = k >> 6, kin = k & 63;
    float v = 0.f;
    if (n < SW) {
        if (j == 0)      v = W[kin * SW + n] - W[2 * 64 * SW + kin * SW + n];
        else if (j == 1) v = W[64 * SW + kin * SW + n];
        else             v = 2.f * W[2 * 64 * SW + kin * SW + n];
    }
    Wt[n * 192 + k] = f2bf(v);
}

// ---- MFMA GEMM: out = relu(h@Wt_j0 + y1@Wt_j1 + y2@Wt_j2 + b) ----
template<int SW, int NT, int OBF>
__global__ __launch_bounds__(256)
void gemm3_mfma_kernel(const unsigned short* __restrict__ h,
                       const unsigned short* __restrict__ y1,
                       const unsigned short* __restrict__ y2,
                       const unsigned short* __restrict__ Wt,
                       const float* __restrict__ bg, void* __restrict__ outg) {
    int tid = threadIdx.x;
    int w = tid >> 6, l = tid & 63;
    int m = l & 15, kg = l >> 4;
    int node = blockIdx.x * 64 + w * 16 + m;
    int nclamp = node < NN ? node : NN - 1;

    f32x4 acc[NT];
    #pragma unroll
    for (int t = 0; t < NT; ++t) acc[t] = (f32x4){0.f, 0.f, 0.f, 0.f};

    #pragma unroll
    for (int ks = 0; ks < 6; ++ks) {
        const unsigned short* src = (ks < 2) ? h : (ks < 4 ? y1 : y2);
        int kin = (ks & 1) * 32 + kg * 8;
        bf16x8 af = *(const bf16x8*)(src + (size_t)nclamp * DH + kin);
        #pragma unroll
        for (int t = 0; t < NT; ++t) {
            const bf16x8* pb = (const bf16x8*)(Wt + ((size_t)(t * 16 + m) * 192 + ks * 32 + kg * 8));
            acc[t] = __builtin_amdgcn_mfma_f32_16x16x32_bf16(af, *pb, acc[t], 0, 0, 0);
        }
    }

    int orow = blockIdx.x * 64 + w * 16 + kg * 4;   // + r
    #pragma unroll
    for (int t = 0; t < NT; ++t) {
        int oc = t * 16 + m;
        float bias = (oc < SW) ? bg[oc] : 0.f;
        #pragma unroll
        for (int r = 0; r < 4; ++r) {
            int nd = orow + r;
            if (nd < NN && oc < SW) {
                float v = fmaxf(acc[t][r] + bias, 0.f);
                if (OBF) ((unsigned short*)outg)[(size_t)nd * SW + oc] = f2bf(v);
                else     ((float*)outg)[(size_t)nd * SW + oc] = v;
            }
        }
    }
}

// ---- in-place log_softmax over last dim (40) ----
__global__ void lsm_kernel(float* __restrict__ out) {
    int g = blockIdx.x * blockDim.x + threadIdx.x;
    int node = g >> 6, lane = g & 63;
    if (node >= NN) return;
    float v = lane < DO ? out[node * DO + lane] : -INFINITY;
    float m = v;
    #pragma unroll
    for (int off = 32; off > 0; off >>= 1) m = fmaxf(m, __shfl_xor(m, off));
    float ex = lane < DO ? __expf(v - m) : 0.f;
    float s = ex;
    #pragma unroll
    for (int off = 32; off > 0; off >>= 1) s += __shfl_xor(s, off);
    if (lane < DO) out[node * DO + lane] = v - m - __logf(s);
}

extern "C" void kernel_launch(void* const* d_in, const int* in_sizes, int n_in,
                              void* d_out, int out_size, void* d_ws, size_t ws_size,
                              hipStream_t stream) {
    const float* x  = (const float*)d_in[0];
    const int*   ei = (const int*)d_in[1];
    const float* ea = (const float*)d_in[2];
    const float* W0 = (const float*)d_in[3];
    const float* b0 = (const float*)d_in[4];
    const float* W1 = (const float*)d_in[5];
    const float* b1 = (const float*)d_in[6];
    const float* W2 = (const float*)d_in[7];
    const float* b2 = (const float*)d_in[8];
    float* out = (float*)d_out;

    const int* row = ei;
    const int* col = ei + NE;

    const size_t HB2 = (size_t)NN * DH * 2;     // bf16 node-feature buffer
    char* p = (char*)d_ws;
    int*   rbptr  = (int*)p;  p += (size_t)(NRB + 4) * 4;
    int2*  epack  = (int2*)p; p += (size_t)NE * 8;
    int2*  binned = (int2*)p; p += (size_t)NE * 8;
    float* dinv   = (float*)p; p += (size_t)NN * 4;
    int*   bcnt   = (int*)p;  p += (size_t)(NBKT + 4) * 4;
    int*   bbase  = (int*)p;  p += (size_t)(NBKT + 4) * 4;
    int*   gcur   = (int*)p;  p += (size_t)(NBKT + 4) * 4;
    unsigned short* xb  = (unsigned short*)p; p += HB2;
    unsigned short* y1b = (unsigned short*)p; p += HB2;
    unsigned short* y2b = (unsigned short*)p; p += HB2;
    unsigned short* hAb = (unsigned short*)p; p += HB2;
    unsigned short* hBb = (unsigned short*)p; p += HB2;
    unsigned short* Wt0 = (unsigned short*)p; p += (size_t)64 * 192 * 2;
    unsigned short* Wt1 = (unsigned short*)p; p += (size_t)64 * 192 * 2;
    unsigned short* Wt2 = (unsigned short*)p; p += (size_t)64 * 192 * 2;

    // ---- weight prep + x conversion (tiny) ----
    wprep_kernel<<<48, 256, 0, stream>>>(W0, 64, Wt0);
    wprep_kernel<<<48, 256, 0, stream>>>(W1, 64, Wt1);
    wprep_kernel<<<48, 256, 0, stream>>>(W2, 40, Wt2);
    x2bf_kernel<<<(NN * DH / 4 + 255) / 256, 256, 0, stream>>>(x, xb);

    // ---- binned CSR build, col-window-sorted within 64-row tiles ----
    hipMemsetAsync(bcnt, 0, (size_t)NBKT * 4, stream);
    bin_count_kernel<<<P3B, 1024, 0, stream>>>(row, bcnt);
    bscan_kernel<<<1, 512, 0, stream>>>(bcnt, bbase, gcur, rbptr);
    bin_scatter_kernel<<<P3B, 1024, 0, stream>>>(row, col, ea, gcur, binned);
    bfin2_kernel<<<NBKT, 1024, 0, stream>>>(bbase, binned, rbptr, dinv, epack);
    env_kernel<<<(NE + 255) / 256, 256, 0, stream>>>(dinv, epack);

    const int GEMM_GRID = (NN + 63) / 64;

    // ---- layer 0 (h = xb) ----
    spmv_tile_kernel<<<NRB, 256, 0, stream>>>(rbptr, epack, xb, y1b);
    spmv_tile_kernel<<<NRB, 256, 0, stream>>>(rbptr, epack, y1b, y2b);
    gemm3_mfma_kernel<64, 4, 1><<<GEMM_GRID, 256, 0, stream>>>(xb, y1b, y2b, Wt0, b0, hAb);

    // ---- layer 1 (h = hAb) ----
    spmv_tile_kernel<<<NRB, 256, 0, stream>>>(rbptr, epack, hAb, y1b);
    spmv_tile_kernel<<<NRB, 256, 0, stream>>>(rbptr, epack, y1b, y2b);
    gemm3_mfma_kernel<64, 4, 1><<<GEMM_GRID, 256, 0, stream>>>(hAb, y1b, y2b, Wt1, b1, hBb);

    // ---- layer 2 (h = hBb) -> f32 logits into d_out ----
    spmv_tile_kernel<<<NRB, 256, 0, stream>>>(rbptr, epack, hBb, y1b);
    spmv_tile_kernel<<<NRB, 256, 0, stream>>>(rbptr, epack, y1b, y2b);
    gemm3_mfma_kernel<40, 3, 0><<<GEMM_GRID, 256, 0, stream>>>(hBb, y1b, y2b, Wt2, b2, out);

    // ---- log_softmax in place ----
    lsm_kernel<<<(NN * 64 + 255) / 256, 256, 0, stream>>>(out);
}

// Round 10
// 480.076 us; speedup vs baseline: 8.2283x; 8.2283x over previous
//
#include <hip/hip_runtime.h>
#include <math.h>

#define NN 100000
#define NE 1600000
#define DH 64
#define DO 40
#define NBKT ((NN + 255) >> 8)                 // 391 buckets of 256 rows
#define P3B 256                                 // blocks in binning passes
#define EPB ((NE + P3B - 1) / P3B)              // 6250 edges per block (exact)

typedef __attribute__((ext_vector_type(8))) short bf16x8;
typedef __attribute__((ext_vector_type(4))) float f32x4;
typedef __attribute__((ext_vector_type(4))) unsigned short u16x4;

__device__ inline unsigned short f2bf(float f) {   // fp32 -> bf16 RNE
    unsigned u = __float_as_uint(f);
    u = (u + 0x7FFF + ((u >> 16) & 1)) >> 16;
    return (unsigned short)u;
}
__device__ inline float bf2f(unsigned short b) {
    return __uint_as_float((unsigned)b << 16);
}

// ---- pass 1: bucket histogram (LDS-aggregated; ~100K global atomics) ----
__global__ __launch_bounds__(1024) void bin_count_kernel(const int* __restrict__ row,
                                                         int* __restrict__ bcnt) {
    __shared__ int h[NBKT];
    for (int i = threadIdx.x; i < NBKT; i += 1024) h[i] = 0;
    __syncthreads();
    int base = blockIdx.x * EPB;
    int end = base + EPB; if (end > NE) end = NE;
    for (int e = base + threadIdx.x; e < end; e += 1024)
        atomicAdd(&h[row[e] >> 8], 1);
    __syncthreads();
    for (int i = threadIdx.x; i < NBKT; i += 1024)
        if (h[i]) atomicAdd(&bcnt[i], h[i]);
}

// ---- pass 2: scan bucket counts -> bbase, gcur; set ptr[NN] ----
__global__ __launch_bounds__(512) void bscan_kernel(const int* __restrict__ bcnt,
                                                    int* __restrict__ bbase,
                                                    int* __restrict__ gcur,
                                                    int* __restrict__ ptr) {
    __shared__ int tmp[512];
    int tid = threadIdx.x;
    int v = (tid < NBKT) ? bcnt[tid] : 0;
    tmp[tid] = v;
    __syncthreads();
    for (int off = 1; off < 512; off <<= 1) {
        int t = (tid >= off) ? tmp[tid - off] : 0;
        __syncthreads();
        tmp[tid] += t;
        __syncthreads();
    }
    if (tid < NBKT) { int excl = tmp[tid] - v; bbase[tid] = excl; gcur[tid] = excl; }
    if (tid == 0) { bbase[NBKT] = NE; ptr[NN] = NE; }
}

// ---- pass 3: scatter edges to bucket-contiguous order (LDS cursors) ----
// binned[pos] = ( (row_local<<17) | col , w )
__global__ __launch_bounds__(1024) void bin_scatter_kernel(const int* __restrict__ row,
                                                           const int* __restrict__ col,
                                                           const float* __restrict__ w,
                                                           int* __restrict__ gcur,
                                                           int2* __restrict__ binned) {
    __shared__ int h[NBKT];
    __shared__ int cur[NBKT];
    for (int i = threadIdx.x; i < NBKT; i += 1024) h[i] = 0;
    __syncthreads();
    int base = blockIdx.x * EPB;
    int end = base + EPB; if (end > NE) end = NE;
    for (int e = base + threadIdx.x; e < end; e += 1024)
        atomicAdd(&h[row[e] >> 8], 1);
    __syncthreads();
    for (int i = threadIdx.x; i < NBKT; i += 1024)
        cur[i] = h[i] ? atomicAdd(&gcur[i], h[i]) : 0;
    __syncthreads();
    for (int e = base + threadIdx.x; e < end; e += 1024) {
        int r = row[e];
        int b = r >> 8;
        int pos = atomicAdd(&cur[b], 1);
        binned[pos] = make_int2(((r & 255) << 17) | col[e], __float_as_int(w[e]));
    }
}

// ---- pass 4: per-bucket CSR finalize: cnt/deg in LDS, scan, ptr, dinv,
//      place edges with partial weight t = -w * dinv[row] ----
__global__ __launch_bounds__(1024) void bfin_kernel(const int* __restrict__ bbase,
                                                    const int2* __restrict__ binned,
                                                    int* __restrict__ ptr,
                                                    float* __restrict__ dinv,
                                                    int2* __restrict__ epack) {
    __shared__ int cnt[256];
    __shared__ float deg[256];
    __shared__ int tmp[256];
    __shared__ int cur[256];
    __shared__ float sdv[256];
    int b = blockIdx.x;
    int s = bbase[b], t = bbase[b + 1];
    int tid = threadIdx.x;
    if (tid < 256) { cnt[tid] = 0; deg[tid] = 0.f; }
    __syncthreads();
    for (int i = s + tid; i < t; i += 1024) {
        int2 ep = binned[i];
        int rl = ((unsigned)ep.x) >> 17;
        atomicAdd(&cnt[rl], 1);
        atomicAdd(&deg[rl], __int_as_float(ep.y));
    }
    __syncthreads();
    if (tid < 256) tmp[tid] = cnt[tid];
    __syncthreads();
    for (int off = 1; off < 256; off <<= 1) {
        int tv = 0;
        if (tid < 256 && tid >= off) tv = tmp[tid - off];
        __syncthreads();
        if (tid < 256) tmp[tid] += tv;
        __syncthreads();
    }
    if (tid < 256) {
        int excl = tmp[tid] - cnt[tid];
        cur[tid] = excl;
        float d = deg[tid];
        float dv = d > 0.f ? 1.0f / sqrtf(d) : 0.f;
        sdv[tid] = dv;
        int r = (b << 8) + tid;
        if (r < NN) { ptr[r] = s + excl; dinv[r] = dv; }
    }
    __syncthreads();
    for (int i = s + tid; i < t; i += 1024) {
        int2 ep = binned[i];
        int rl = ((unsigned)ep.x) >> 17;
        int c = ep.x & 0x1FFFF;
        int lr = atomicAdd(&cur[rl], 1);
        float tp = -__int_as_float(ep.y) * sdv[rl];
        epack[s + lr] = make_int2(c, __float_as_int(tp));
    }
}

// ---- pass 5: env finalize: nv = t * dinv[col] ----
__global__ void env_kernel(const float* __restrict__ dinv, int2* __restrict__ epack) {
    int e = blockIdx.x * blockDim.x + threadIdx.x;
    if (e < NE) {
        int2 ep = epack[e];
        ep.y = __float_as_int(__int_as_float(ep.y) * dinv[ep.x]);
        epack[e] = ep;
    }
}

// ---- x (f32) -> xb (bf16) ----
__global__ void x2bf_kernel(const float* __restrict__ x, unsigned short* __restrict__ xb) {
    int i = blockIdx.x * blockDim.x + threadIdx.x;
    if (i < NN * DH / 4) {
        float4 v = ((const float4*)x)[i];
        u16x4 o = {f2bf(v.x), f2bf(v.y), f2bf(v.z), f2bf(v.w)};
        ((u16x4*)xb)[i] = o;
    }
}

// ---- CSR SpMV: one wave per row, lane = feature. Edge metadata loaded via
// SCALAR loads (wave-uniform index, readfirstlane-forced) -> no shfl, no LDS
// queue; 16 gathers in flight per wave. ----
__global__ __launch_bounds__(256) void spmv_csr_kernel(const int* __restrict__ ptr,
                                                       const int2* __restrict__ epack,
                                                       const unsigned short* __restrict__ h,
                                                       unsigned short* __restrict__ y) {
    int g = blockIdx.x * blockDim.x + threadIdx.x;
    int r = __builtin_amdgcn_readfirstlane(g >> 6);
    int lane = threadIdx.x & 63;
    if (r >= NN) return;
    int s = ptr[r], t = ptr[r + 1];
    float a0 = 0.f, a1 = 0.f, a2 = 0.f, a3 = 0.f;
    float a4 = 0.f, a5 = 0.f, a6 = 0.f, a7 = 0.f;
    int i = s;
    for (; i + 16 <= t; i += 16) {
        int2 e0 = epack[i];      int2 e1 = epack[i + 1];
        int2 e2 = epack[i + 2];  int2 e3 = epack[i + 3];
        int2 e4 = epack[i + 4];  int2 e5 = epack[i + 5];
        int2 e6 = epack[i + 6];  int2 e7 = epack[i + 7];
        int2 e8 = epack[i + 8];  int2 e9 = epack[i + 9];
        int2 eA = epack[i + 10]; int2 eB = epack[i + 11];
        int2 eC = epack[i + 12]; int2 eD = epack[i + 13];
        int2 eE = epack[i + 14]; int2 eF = epack[i + 15];
        unsigned short h0 = h[(size_t)e0.x * DH + lane];
        unsigned short h1 = h[(size_t)e1.x * DH + lane];
        unsigned short h2 = h[(size_t)e2.x * DH + lane];
        unsigned short h3 = h[(size_t)e3.x * DH + lane];
        unsigned short h4 = h[(size_t)e4.x * DH + lane];
        unsigned short h5 = h[(size_t)e5.x * DH + lane];
        unsigned short h6 = h[(size_t)e6.x * DH + lane];
        unsigned short h7 = h[(size_t)e7.x * DH + lane];
        unsigned short h8 = h[(size_t)e8.x * DH + lane];
        unsigned short h9 = h[(size_t)e9.x * DH + lane];
        unsigned short hA = h[(size_t)eA.x * DH + lane];
        unsigned short hB = h[(size_t)eB.x * DH + lane];
        unsigned short hC = h[(size_t)eC.x * DH + lane];
        unsigned short hD = h[(size_t)eD.x * DH + lane];
        unsigned short hE = h[(size_t)eE.x * DH + lane];
        unsigned short hF = h[(size_t)eF.x * DH + lane];
        a0 = fmaf(__int_as_float(e0.y), bf2f(h0), a0);
        a1 = fmaf(__int_as_float(e1.y), bf2f(h1), a1);
        a2 = fmaf(__int_as_float(e2.y), bf2f(h2), a2);
        a3 = fmaf(__int_as_float(e3.y), bf2f(h3), a3);
        a4 = fmaf(__int_as_float(e4.y), bf2f(h4), a4);
        a5 = fmaf(__int_as_float(e5.y), bf2f(h5), a5);
        a6 = fmaf(__int_as_float(e6.y), bf2f(h6), a6);
        a7 = fmaf(__int_as_float(e7.y), bf2f(h7), a7);
        a0 = fmaf(__int_as_float(e8.y), bf2f(h8), a0);
        a1 = fmaf(__int_as_float(e9.y), bf2f(h9), a1);
        a2 = fmaf(__int_as_float(eA.y), bf2f(hA), a2);
        a3 = fmaf(__int_as_float(eB.y), bf2f(hB), a3);
        a4 = fmaf(__int_as_float(eC.y), bf2f(hC), a4);
        a5 = fmaf(__int_as_float(eD.y), bf2f(hD), a5);
        a6 = fmaf(__int_as_float(eE.y), bf2f(hE), a6);
        a7 = fmaf(__int_as_float(eF.y), bf2f(hF), a7);
    }
    for (; i + 4 <= t; i += 4) {
        int2 e0 = epack[i];     int2 e1 = epack[i + 1];
        int2 e2 = epack[i + 2]; int2 e3 = epack[i + 3];
        unsigned short h0 = h[(size_t)e0.x * DH + lane];
        unsigned short h1 = h[(size_t)e1.x * DH + lane];
        unsigned short h2 = h[(size_t)e2.x * DH + lane];
        unsigned short h3 = h[(size_t)e3.x * DH + lane];
        a0 = fmaf(__int_as_float(e0.y), bf2f(h0), a0);
        a1 = fmaf(__int_as_float(e1.y), bf2f(h1), a1);
        a2 = fmaf(__int_as_float(e2.y), bf2f(h2), a2);
        a3 = fmaf(__int_as_float(e3.y), bf2f(h3), a3);
    }
    for (; i < t; ++i) {
        int2 e = epack[i];
        a0 = fmaf(__int_as_float(e.y), bf2f(h[(size_t)e.x * DH + lane]), a0);
    }
    float res = ((a0 + a1) + (a2 + a3)) + ((a4 + a5) + (a6 + a7));
    y[(size_t)r * DH + lane] = f2bf(res);
}

// ---- weight prep: Wt[n][192] bf16, k = j*64+kin ----
// j=0: W[0]-W[2]; j=1: W[1]; j=2: 2*W[2]   (folds Tx2 = 2*y2 - Tx0 into weights)
__global__ void wprep_kernel(const float* __restrict__ W, int SW,
                             unsigned short* __restrict__ Wt) {
    int idx = blockIdx.x * 256 + threadIdx.x;
    if (idx >= 64 * 192) return;
    int n = idx / 192, k = idx - n * 192;
    int j = k >> 6, kin = k & 63;
    float v = 0.f;
    if (n < SW) {
        if (j == 0)      v = W[kin * SW + n] - W[2 * 64 * SW + kin * SW + n];
        else if (j == 1) v = W[64 * SW + kin * SW + n];
        else             v = 2.f * W[2 * 64 * SW + kin * SW + n];
    }
    Wt[n * 192 + k] = f2bf(v);
}

// ---- MFMA GEMM: out = relu(h@Wt_j0 + y1@Wt_j1 + y2@Wt_j2 + b) ----
template<int SW, int NT, int OBF>
__global__ __launch_bounds__(256)
void gemm3_mfma_kernel(const unsigned short* __restrict__ h,
                       const unsigned short* __restrict__ y1,
                       const unsigned short* __restrict__ y2,
                       const unsigned short* __restrict__ Wt,
                       const float* __restrict__ bg, void* __restrict__ outg) {
    int tid = threadIdx.x;
    int w = tid >> 6, l = tid & 63;
    int m = l & 15, kg = l >> 4;
    int node = blockIdx.x * 64 + w * 16 + m;
    int nclamp = node < NN ? node : NN - 1;

    f32x4 acc[NT];
    #pragma unroll
    for (int t = 0; t < NT; ++t) acc[t] = (f32x4){0.f, 0.f, 0.f, 0.f};

    #pragma unroll
    for (int ks = 0; ks < 6; ++ks) {
        const unsigned short* src = (ks < 2) ? h : (ks < 4 ? y1 : y2);
        int kin = (ks & 1) * 32 + kg * 8;
        bf16x8 af = *(const bf16x8*)(src + (size_t)nclamp * DH + kin);
        #pragma unroll
        for (int t = 0; t < NT; ++t) {
            const bf16x8* pb = (const bf16x8*)(Wt + ((size_t)(t * 16 + m) * 192 + ks * 32 + kg * 8));
            acc[t] = __builtin_amdgcn_mfma_f32_16x16x32_bf16(af, *pb, acc[t], 0, 0, 0);
        }
    }

    int orow = blockIdx.x * 64 + w * 16 + kg * 4;   // + r
    #pragma unroll
    for (int t = 0; t < NT; ++t) {
        int oc = t * 16 + m;
        float bias = (oc < SW) ? bg[oc] : 0.f;
        #pragma unroll
        for (int r = 0; r < 4; ++r) {
            int nd = orow + r;
            if (nd < NN && oc < SW) {
                float v = fmaxf(acc[t][r] + bias, 0.f);
                if (OBF) ((unsigned short*)outg)[(size_t)nd * SW + oc] = f2bf(v);
                else     ((float*)outg)[(size_t)nd * SW + oc] = v;
            }
        }
    }
}

// ---- in-place log_softmax over last dim (40) ----
__global__ void lsm_kernel(float* __restrict__ out) {
    int g = blockIdx.x * blockDim.x + threadIdx.x;
    int node = g >> 6, lane = g & 63;
    if (node >= NN) return;
    float v = lane < DO ? out[node * DO + lane] : -INFINITY;
    float m = v;
    #pragma unroll
    for (int off = 32; off > 0; off >>= 1) m = fmaxf(m, __shfl_xor(m, off));
    float ex = lane < DO ? __expf(v - m) : 0.f;
    float s = ex;
    #pragma unroll
    for (int off = 32; off > 0; off >>= 1) s += __shfl_xor(s, off);
    if (lane < DO) out[node * DO + lane] = v - m - __logf(s);
}

extern "C" void kernel_launch(void* const* d_in, const int* in_sizes, int n_in,
                              void* d_out, int out_size, void* d_ws, size_t ws_size,
                              hipStream_t stream) {
    const float* x  = (const float*)d_in[0];
    const int*   ei = (const int*)d_in[1];
    const float* ea = (const float*)d_in[2];
    const float* W0 = (const float*)d_in[3];
    const float* b0 = (const float*)d_in[4];
    const float* W1 = (const float*)d_in[5];
    const float* b1 = (const float*)d_in[6];
    const float* W2 = (const float*)d_in[7];
    const float* b2 = (const float*)d_in[8];
    float* out = (float*)d_out;

    const int* row = ei;
    const int* col = ei + NE;

    const size_t HB2 = (size_t)NN * DH * 2;     // bf16 node-feature buffer
    char* p = (char*)d_ws;
    int*   ptr    = (int*)p;  p += (size_t)(NN + 4) * 4;
    int2*  epack  = (int2*)p; p += (size_t)NE * 8;
    int2*  binned = (int2*)p; p += (size_t)NE * 8;
    float* dinv   = (float*)p; p += (size_t)NN * 4;
    int*   bcnt   = (int*)p;  p += (size_t)(NBKT + 4) * 4;
    int*   bbase  = (int*)p;  p += (size_t)(NBKT + 4) * 4;
    int*   gcur   = (int*)p;  p += (size_t)(NBKT + 4) * 4;
    unsigned short* xb  = (unsigned short*)p; p += HB2;
    unsigned short* y1b = (unsigned short*)p; p += HB2;
    unsigned short* y2b = (unsigned short*)p; p += HB2;
    unsigned short* hAb = (unsigned short*)p; p += HB2;
    unsigned short* hBb = (unsigned short*)p; p += HB2;
    unsigned short* Wt0 = (unsigned short*)p; p += (size_t)64 * 192 * 2;
    unsigned short* Wt1 = (unsigned short*)p; p += (size_t)64 * 192 * 2;
    unsigned short* Wt2 = (unsigned short*)p; p += (size_t)64 * 192 * 2;

    // ---- weight prep + x conversion (tiny) ----
    wprep_kernel<<<48, 256, 0, stream>>>(W0, 64, Wt0);
    wprep_kernel<<<48, 256, 0, stream>>>(W1, 64, Wt1);
    wprep_kernel<<<48, 256, 0, stream>>>(W2, 40, Wt2);
    x2bf_kernel<<<(NN * DH / 4 + 255) / 256, 256, 0, stream>>>(x, xb);

    // ---- binned CSR build (~200K global atomics instead of 1.6M) ----
    hipMemsetAsync(bcnt, 0, (size_t)NBKT * 4, stream);
    bin_count_kernel<<<P3B, 1024, 0, stream>>>(row, bcnt);
    bscan_kernel<<<1, 512, 0, stream>>>(bcnt, bbase, gcur, ptr);
    bin_scatter_kernel<<<P3B, 1024, 0, stream>>>(row, col, ea, gcur, binned);
    bfin_kernel<<<NBKT, 1024, 0, stream>>>(bbase, binned, ptr, dinv, epack);
    env_kernel<<<(NE + 255) / 256, 256, 0, stream>>>(dinv, epack);

    const int SPMV_GRID = (NN * 64 + 255) / 256;
    const int GEMM_GRID = (NN + 63) / 64;

    // ---- layer 0 (h = xb) ----
    spmv_csr_kernel<<<SPMV_GRID, 256, 0, stream>>>(ptr, epack, xb, y1b);
    spmv_csr_kernel<<<SPMV_GRID, 256, 0, stream>>>(ptr, epack, y1b, y2b);
    gemm3_mfma_kernel<64, 4, 1><<<GEMM_GRID, 256, 0, stream>>>(xb, y1b, y2b, Wt0, b0, hAb);

    // ---- layer 1 (h = hAb) ----
    spmv_csr_kernel<<<SPMV_GRID, 256, 0, stream>>>(ptr, epack, hAb, y1b);
    spmv_csr_kernel<<<SPMV_GRID, 256, 0, stream>>>(ptr, epack, y1b, y2b);
    gemm3_mfma_kernel<64, 4, 1><<<GEMM_GRID, 256, 0, stream>>>(hAb, y1b, y2b, Wt1, b1, hBb);

    // ---- layer 2 (h = hBb) -> f32 logits into d_out ----
    spmv_csr_kernel<<<SPMV_GRID, 256, 0, stream>>>(ptr, epack, hBb, y1b);
    spmv_csr_kernel<<<SPMV_GRID, 256, 0, stream>>>(ptr, epack, y1b, y2b);
    gemm3_mfma_kernel<40, 3, 0><<<GEMM_GRID, 256, 0, stream>>>(hBb, y1b, y2b, Wt2, b2, out);

    // ---- log_softmax in place ----
    lsm_kernel<<<(NN * 64 + 255) / 256, 256, 0, stream>>>(out);
}